// Round 9
// baseline (24.858 us; speedup 1.0000x reference)
//
#include <hip/hip_runtime.h>

#define NB 4
#define NS 1024
#define NE 128
#define NH 16
#define ND 8

typedef __attribute__((ext_vector_type(4))) _Float16 half4v;
typedef __attribute__((ext_vector_type(8))) _Float16 half8v;
typedef __attribute__((ext_vector_type(2))) _Float16 half2v;
typedef __attribute__((ext_vector_type(4))) float float4v;

// 2^x with BOTH branches native: builtin v_exp_f32 if available, else
// __expf(ln2*x) = v_mul_f32 + v_exp_f32 (never the ocml libm path).
#if __has_builtin(__builtin_amdgcn_exp2f)
#define EXP2F(x) __builtin_amdgcn_exp2f(x)
#else
#define EXP2F(x) __expf(0.69314718055994531f * (x))
#endif

// sqrt(log2(e)/sqrt(8)): both QK^T operands carry this -> MFMA out feeds 2^x directly
#define SQRT_ALPHA 0.71423656f

// ---------------------------------------------------------------------------
// Fused quantum-layer + self-attention via f16 MFMA, LDS-traffic-minimized.
// proj[0]=g1*...*g7, proj[w]=g0*...*gw with g_j=cos(x_j+phi_j)  (closed form).
// S^T = K.Q^T via mfma 16x16x16: lane holds P[q=l&15][keys (l>>4)*4+r] ->
// exactly the PV A-fragment after exp2+cvt_pkrtz (no LDS bounce for P).
// V staged transposed with a ones-row (col 8 of output = softmax denom).
//
// KEY CHANGE (R9): kf/vf fragments are q-subtile-independent, but previous
// rounds had every wave re-reading them -> ~2048 ds_reads/CU-pass saturating
// the per-CU LDS pipe (~12-16K cy = 5-7us; explains R5-R8 null results).
// Now each wave owns FOUR q-subtiles (4 qf, 4 acc in regs) per kf/vf read:
// 8x fewer LDS reads. Block = 8 waves = (qg 0..1) x (kh 0..3: 256-key range).
// kh-partials (unnormalized, incl. denom col) combined via 16KB LDS tree,
// 2 barriers. LDS 50.2KB -> up to 3 blocks/CU.
// ---------------------------------------------------------------------------
__global__ __launch_bounds__(512, 4)
void qattn_kernel(const float* __restrict__ x, const float* __restrict__ phi,
                  float* __restrict__ aout)
{
    __shared__ __align__(16) _Float16 Klds[NS][8];      // 16 KB, scaled by SQRT_ALPHA
    __shared__ __align__(16) _Float16 Vt[9][1036];      // 18.2 KB: rows0-7 raw k, row8 ones
    __shared__ __align__(16) float4 scratch[2][2][4][64]; // 16 KB partial tree

    const int t    = threadIdx.x;
    const int blk  = blockIdx.x;
    const int qt   = blk & 7;          // 128-query tile
    const int bh   = blk >> 3;
    const int b    = bh >> 4;
    const int h    = bh & 15;
    const int lane = t & 63;
    const int w    = t >> 6;           // 0..7
    const int qg   = w & 1;            // q-subtile group: qsubs qg*4..qg*4+3
    const int kh   = w >> 1;           // key quarter: [kh*256, kh*256+256)

    const float ph0 = phi[0], ph1 = phi[1], ph2 = phi[2], ph3 = phi[3];
    const float ph4 = phi[4], ph5 = phi[5], ph6 = phi[6], ph7 = phi[7];

    // ---- stage K (scaled) and V^T (raw + ones row): two rows per thread ----
    {
        const float* xb = x + ((size_t)b * NS) * NE + h * ND;
        const int k0 = t, k1 = t + 512;
        float4 xa0 = *(const float4*)(xb + (size_t)k0 * NE);
        float4 xc0 = *(const float4*)(xb + (size_t)k0 * NE + 4);
        float4 xa1 = *(const float4*)(xb + (size_t)k1 * NE);
        float4 xc1 = *(const float4*)(xb + (size_t)k1 * NE + 4);
#pragma unroll
        for (int half = 0; half < 2; ++half) {
            const int k = half ? k1 : k0;
            const float4 xa = half ? xa1 : xa0;
            const float4 xc = half ? xc1 : xc0;
            float g0 = __cosf(xa.x + ph0), g1 = __cosf(xa.y + ph1);
            float g2 = __cosf(xa.z + ph2), g3 = __cosf(xa.w + ph3);
            float g4 = __cosf(xc.x + ph4), g5 = __cosf(xc.y + ph5);
            float g6 = __cosf(xc.z + ph6), g7 = __cosf(xc.w + ph7);
            float s7 = g7, s6 = s7 * g6, s5 = s6 * g5, s4 = s5 * g4, s3 = s4 * g3, s2 = s3 * g2;
            float v0 = s2 * g1;                         // wire 0 expectation
            float v1 = g0 * g1, v2 = v1 * g2, v3 = v2 * g3;
            float v4 = v3 * g4, v5 = v4 * g5, v6 = v5 * g6, v7 = v6 * g7;
            half8v row;
            row[0] = (_Float16)(SQRT_ALPHA * v0); row[1] = (_Float16)(SQRT_ALPHA * v1);
            row[2] = (_Float16)(SQRT_ALPHA * v2); row[3] = (_Float16)(SQRT_ALPHA * v3);
            row[4] = (_Float16)(SQRT_ALPHA * v4); row[5] = (_Float16)(SQRT_ALPHA * v5);
            row[6] = (_Float16)(SQRT_ALPHA * v6); row[7] = (_Float16)(SQRT_ALPHA * v7);
            *(half8v*)&Klds[k][0] = row;
            Vt[0][k] = (_Float16)v0; Vt[1][k] = (_Float16)v1;
            Vt[2][k] = (_Float16)v2; Vt[3][k] = (_Float16)v3;
            Vt[4][k] = (_Float16)v4; Vt[5][k] = (_Float16)v5;
            Vt[6][k] = (_Float16)v6; Vt[7][k] = (_Float16)v7;
            Vt[8][k] = (_Float16)1.0f;
        }
    }
    __syncthreads();

    const int e = lane & 15;
    const int g = lane >> 4;

    // Q fragments (B operand of S^T): B[kd][q], kd=(l>>4)*4+j, q=l&15.
    // Lanes >=32 cover kd 8..15 -> zero (kills garbage K products too).
    half4v qf0 = (half4v)(_Float16)0.0f;
    half4v qf1 = (half4v)(_Float16)0.0f;
    half4v qf2 = (half4v)(_Float16)0.0f;
    half4v qf3 = (half4v)(_Float16)0.0f;
    if (lane < 32) {
        const int qbase = qt * 128 + qg * 64 + e;
        qf0 = *(const half4v*)&Klds[qbase][g * 4];
        qf1 = *(const half4v*)&Klds[qbase + 16][g * 4];
        qf2 = *(const half4v*)&Klds[qbase + 32][g * 4];
        qf3 = *(const half4v*)&Klds[qbase + 48][g * 4];
    }

    const _Float16* kp = &Klds[kh * 256 + e][(g & 1) * 4]; // A: K[koff+tt*16+(l&15)][(l>>4)*4+j]
    const int ecl = (e > 8) ? 8 : e;                       // clamp: cols 9..15 unread
    const _Float16* vp = &Vt[ecl][kh * 256 + g * 4];       // B_V: V[koff+tt*16+(l>>4)*4+j][e]

    float4v acc0 = (float4v)0.0f;
    float4v acc1 = (float4v)0.0f;
    float4v acc2 = (float4v)0.0f;
    float4v acc3 = (float4v)0.0f;
    const float4v zero = (float4v)0.0f;

    // 16 key-tiles of 16; ONE kf/vf read feeds 4 q-subtiles.
#pragma unroll 4
    for (int tt = 0; tt < 16; ++tt) {
        half4v kf = *(const half4v*)(kp + tt * 128);
        half4v vf = *(const half4v*)(vp + tt * 16);

        float4v s0 = __builtin_amdgcn_mfma_f32_16x16x16f16(kf, qf0, zero, 0, 0, 0);
        float4v s1 = __builtin_amdgcn_mfma_f32_16x16x16f16(kf, qf1, zero, 0, 0, 0);
        float4v s2 = __builtin_amdgcn_mfma_f32_16x16x16f16(kf, qf2, zero, 0, 0, 0);
        float4v s3 = __builtin_amdgcn_mfma_f32_16x16x16f16(kf, qf3, zero, 0, 0, 0);

        float p00 = EXP2F(s0[0]), p01 = EXP2F(s0[1]), p02 = EXP2F(s0[2]), p03 = EXP2F(s0[3]);
        float p10 = EXP2F(s1[0]), p11 = EXP2F(s1[1]), p12 = EXP2F(s1[2]), p13 = EXP2F(s1[3]);
        float p20 = EXP2F(s2[0]), p21 = EXP2F(s2[1]), p22 = EXP2F(s2[2]), p23 = EXP2F(s2[3]);
        float p30 = EXP2F(s3[0]), p31 = EXP2F(s3[1]), p32 = EXP2F(s3[2]), p33 = EXP2F(s3[3]);

        half2v lo0 = __builtin_bit_cast(half2v, __builtin_amdgcn_cvt_pkrtz(p00, p01));
        half2v hi0 = __builtin_bit_cast(half2v, __builtin_amdgcn_cvt_pkrtz(p02, p03));
        half2v lo1 = __builtin_bit_cast(half2v, __builtin_amdgcn_cvt_pkrtz(p10, p11));
        half2v hi1 = __builtin_bit_cast(half2v, __builtin_amdgcn_cvt_pkrtz(p12, p13));
        half2v lo2 = __builtin_bit_cast(half2v, __builtin_amdgcn_cvt_pkrtz(p20, p21));
        half2v hi2 = __builtin_bit_cast(half2v, __builtin_amdgcn_cvt_pkrtz(p22, p23));
        half2v lo3 = __builtin_bit_cast(half2v, __builtin_amdgcn_cvt_pkrtz(p30, p31));
        half2v hi3 = __builtin_bit_cast(half2v, __builtin_amdgcn_cvt_pkrtz(p32, p33));

        half4v pa0 = __builtin_shufflevector(lo0, hi0, 0, 1, 2, 3);
        half4v pa1 = __builtin_shufflevector(lo1, hi1, 0, 1, 2, 3);
        half4v pa2 = __builtin_shufflevector(lo2, hi2, 0, 1, 2, 3);
        half4v pa3 = __builtin_shufflevector(lo3, hi3, 0, 1, 2, 3);

        acc0 = __builtin_amdgcn_mfma_f32_16x16x16f16(pa0, vf, acc0, 0, 0, 0);
        acc1 = __builtin_amdgcn_mfma_f32_16x16x16f16(pa1, vf, acc1, 0, 0, 0);
        acc2 = __builtin_amdgcn_mfma_f32_16x16x16f16(pa2, vf, acc2, 0, 0, 0);
        acc3 = __builtin_amdgcn_mfma_f32_16x16x16f16(pa3, vf, acc3, 0, 0, 0);
    }

    // ---- kh-partial tree (unnormalized sums incl. denom col), 2 barriers ----
    if (kh >= 2) {
        scratch[kh - 2][qg][0][lane] = make_float4(acc0[0], acc0[1], acc0[2], acc0[3]);
        scratch[kh - 2][qg][1][lane] = make_float4(acc1[0], acc1[1], acc1[2], acc1[3]);
        scratch[kh - 2][qg][2][lane] = make_float4(acc2[0], acc2[1], acc2[2], acc2[3]);
        scratch[kh - 2][qg][3][lane] = make_float4(acc3[0], acc3[1], acc3[2], acc3[3]);
    }
    __syncthreads();
    if (kh < 2) {
        float4 c0 = scratch[kh][qg][0][lane];
        float4 c1 = scratch[kh][qg][1][lane];
        float4 c2 = scratch[kh][qg][2][lane];
        float4 c3 = scratch[kh][qg][3][lane];
        acc0[0] += c0.x; acc0[1] += c0.y; acc0[2] += c0.z; acc0[3] += c0.w;
        acc1[0] += c1.x; acc1[1] += c1.y; acc1[2] += c1.z; acc1[3] += c1.w;
        acc2[0] += c2.x; acc2[1] += c2.y; acc2[2] += c2.z; acc2[3] += c2.w;
        acc3[0] += c3.x; acc3[1] += c3.y; acc3[2] += c3.z; acc3[3] += c3.w;
    }
    if (kh == 1) {   // rewrite region [1] (only this wave read it)
        scratch[1][qg][0][lane] = make_float4(acc0[0], acc0[1], acc0[2], acc0[3]);
        scratch[1][qg][1][lane] = make_float4(acc1[0], acc1[1], acc1[2], acc1[3]);
        scratch[1][qg][2][lane] = make_float4(acc2[0], acc2[1], acc2[2], acc2[3]);
        scratch[1][qg][3][lane] = make_float4(acc3[0], acc3[1], acc3[2], acc3[3]);
    }
    __syncthreads();
    if (kh == 0) {
        float4 c0 = scratch[1][qg][0][lane];
        float4 c1 = scratch[1][qg][1][lane];
        float4 c2 = scratch[1][qg][2][lane];
        float4 c3 = scratch[1][qg][3][lane];
        acc0[0] += c0.x; acc0[1] += c0.y; acc0[2] += c0.z; acc0[3] += c0.w;
        acc1[0] += c1.x; acc1[1] += c1.y; acc1[2] += c1.z; acc1[3] += c1.w;
        acc2[0] += c2.x; acc2[1] += c2.y; acc2[2] += c2.z; acc2[3] += c2.w;
        acc3[0] += c3.x; acc3[1] += c3.y; acc3[2] += c3.z; acc3[3] += c3.w;

        const int src = (lane & 48) | 8;
        const size_t rb = (size_t)(b * NS + qt * 128 + qg * 64 + g * 4);
        float* opb = aout + rb * NE + h * ND + e;
#pragma unroll
        for (int qs = 0; qs < 4; ++qs) {
            float4v a = (qs == 0) ? acc0 : (qs == 1) ? acc1 : (qs == 2) ? acc2 : acc3;
            float d0 = __shfl(a[0], src, 64);
            float d1 = __shfl(a[1], src, 64);
            float d2 = __shfl(a[2], src, 64);
            float d3 = __shfl(a[3], src, 64);
            if (e < 8) {
                float* op = opb + (size_t)(qs * 16) * NE;
                op[0 * NE] = a[0] / d0;
                op[1 * NE] = a[1] / d1;
                op[2 * NE] = a[2] / d2;
                op[3 * NE] = a[3] / d3;
            }
        }
    }
}

// ---------------------------------------------------------------------------
// out = A @ W^T + b, in place (block reads only the 16 rows it writes).
// 256 blocks x 512 thr. W transposed-staged in two 64-col halves.
// ---------------------------------------------------------------------------
__global__ __launch_bounds__(512)
void proj_kernel(const float* __restrict__ A, const float* __restrict__ W,
                 const float* __restrict__ bias, float* __restrict__ out)
{
    __shared__ float Wt[64][NE + 4];   // transposed half of W, padded (33.8 KB)
    __shared__ float As[16][NE];       // 8 KB

    const int t  = threadIdx.x;
    const int r0 = blockIdx.x * 16;

    for (int i = t; i < 16 * NE; i += 512) {
        As[i >> 7][i & 127] = A[(size_t)(r0 + (i >> 7)) * NE + (i & 127)];
    }

    const int c4 = (t & 31) * 4;
    const int rg = t >> 5;                     // row r0+rg (0..15)
    float acc0 = 0, acc1 = 0, acc2 = 0, acc3 = 0;

    for (int eh = 0; eh < 2; ++eh) {
        if (eh) __syncthreads();               // previous half fully consumed
        for (int i = t; i < NE * 64; i += 512) {
            int c = i >> 6;
            int e = i & 63;
            Wt[e][c] = W[c * NE + eh * 64 + e];
        }
        __syncthreads();
#pragma unroll 8
        for (int e = 0; e < 64; ++e) {
            float4 wv = *(const float4*)&Wt[e][c4];
            float av = As[rg][eh * 64 + e];
            acc0 += av * wv.x; acc1 += av * wv.y;
            acc2 += av * wv.z; acc3 += av * wv.w;
        }
    }

    float4 bv = *(const float4*)&bias[c4];
    float4 o = make_float4(acc0 + bv.x, acc1 + bv.y, acc2 + bv.z, acc3 + bv.w);
    *(float4*)(out + (size_t)(r0 + rg) * NE + c4) = o;
}

extern "C" void kernel_launch(void* const* d_in, const int* in_sizes, int n_in,
                              void* d_out, int out_size, void* d_ws, size_t ws_size,
                              hipStream_t stream)
{
    (void)in_sizes; (void)n_in; (void)out_size; (void)d_ws; (void)ws_size;
    const float* x   = (const float*)d_in[0];
    const float* phi = (const float*)d_in[1];
    const float* W   = (const float*)d_in[2];
    const float* b   = (const float*)d_in[3];
    float* out = (float*)d_out;

    qattn_kernel<<<dim3(NB * NH * 8), dim3(512), 0, stream>>>(x, phi, out);
    proj_kernel<<<dim3(NB * NS / 16), dim3(512), 0, stream>>>(out, W, b, out);
}

// Round 10
// 21.649 us; speedup vs baseline: 1.1482x; 1.1482x over previous
//
#include <hip/hip_runtime.h>

#define NB 4
#define NS 1024
#define NE 128
#define NH 16
#define ND 8

typedef __attribute__((ext_vector_type(4))) _Float16 half4v;
typedef __attribute__((ext_vector_type(8))) _Float16 half8v;
typedef __attribute__((ext_vector_type(2))) _Float16 half2v;
typedef __attribute__((ext_vector_type(4))) float float4v;

// 2^x with BOTH branches native: builtin v_exp_f32 if available, else
// __expf(ln2*x) = v_mul_f32 + v_exp_f32 (never the ocml libm path).
#if __has_builtin(__builtin_amdgcn_exp2f)
#define EXP2F(x) __builtin_amdgcn_exp2f(x)
#else
#define EXP2F(x) __expf(0.69314718055994531f * (x))
#endif

// sqrt(log2(e)/sqrt(8)): both QK^T operands carry this -> MFMA out feeds 2^x directly
#define SQRT_ALPHA 0.71423656f

// ---------------------------------------------------------------------------
// Fused quantum-layer + self-attention via f16 MFMA (structure = R9 + setprio).
// proj[0]=g1*...*g7, proj[w]=g0*...*gw with g_j=cos(x_j+phi_j)  (closed form).
// S^T = K.Q^T via mfma 16x16x16; V^T staged with ones-row (col 8 = denom).
// Each wave owns 4 q-subtiles per kf/vf read; kh-partials via LDS tree.
// ---------------------------------------------------------------------------
__global__ __launch_bounds__(512, 4)
void qattn_kernel(const float* __restrict__ x, const float* __restrict__ phi,
                  float* __restrict__ aout)
{
    __shared__ __align__(16) _Float16 Klds[NS][8];      // 16 KB, scaled by SQRT_ALPHA
    __shared__ __align__(16) _Float16 Vt[9][1036];      // 18.2 KB: rows0-7 raw k, row8 ones
    __shared__ __align__(16) float4 scratch[2][2][4][64]; // 16 KB partial tree

    const int t    = threadIdx.x;
    const int blk  = blockIdx.x;
    const int qt   = blk & 7;          // 128-query tile
    const int bh   = blk >> 3;
    const int b    = bh >> 4;
    const int h    = bh & 15;
    const int lane = t & 63;
    const int w    = t >> 6;           // 0..7
    const int qg   = w & 1;            // q-subtile group: qsubs qg*4..qg*4+3
    const int kh   = w >> 1;           // key quarter: [kh*256, kh*256+256)

    const float ph0 = phi[0], ph1 = phi[1], ph2 = phi[2], ph3 = phi[3];
    const float ph4 = phi[4], ph5 = phi[5], ph6 = phi[6], ph7 = phi[7];

    // ---- stage K (scaled) and V^T (raw + ones row): two rows per thread ----
    {
        const float* xb = x + ((size_t)b * NS) * NE + h * ND;
        const int k0 = t, k1 = t + 512;
        float4 xa0 = *(const float4*)(xb + (size_t)k0 * NE);
        float4 xc0 = *(const float4*)(xb + (size_t)k0 * NE + 4);
        float4 xa1 = *(const float4*)(xb + (size_t)k1 * NE);
        float4 xc1 = *(const float4*)(xb + (size_t)k1 * NE + 4);
#pragma unroll
        for (int half = 0; half < 2; ++half) {
            const int k = half ? k1 : k0;
            const float4 xa = half ? xa1 : xa0;
            const float4 xc = half ? xc1 : xc0;
            float g0 = __cosf(xa.x + ph0), g1 = __cosf(xa.y + ph1);
            float g2 = __cosf(xa.z + ph2), g3 = __cosf(xa.w + ph3);
            float g4 = __cosf(xc.x + ph4), g5 = __cosf(xc.y + ph5);
            float g6 = __cosf(xc.z + ph6), g7 = __cosf(xc.w + ph7);
            float s7 = g7, s6 = s7 * g6, s5 = s6 * g5, s4 = s5 * g4, s3 = s4 * g3, s2 = s3 * g2;
            float v0 = s2 * g1;                         // wire 0 expectation
            float v1 = g0 * g1, v2 = v1 * g2, v3 = v2 * g3;
            float v4 = v3 * g4, v5 = v4 * g5, v6 = v5 * g6, v7 = v6 * g7;
            half8v row;
            row[0] = (_Float16)(SQRT_ALPHA * v0); row[1] = (_Float16)(SQRT_ALPHA * v1);
            row[2] = (_Float16)(SQRT_ALPHA * v2); row[3] = (_Float16)(SQRT_ALPHA * v3);
            row[4] = (_Float16)(SQRT_ALPHA * v4); row[5] = (_Float16)(SQRT_ALPHA * v5);
            row[6] = (_Float16)(SQRT_ALPHA * v6); row[7] = (_Float16)(SQRT_ALPHA * v7);
            *(half8v*)&Klds[k][0] = row;
            Vt[0][k] = (_Float16)v0; Vt[1][k] = (_Float16)v1;
            Vt[2][k] = (_Float16)v2; Vt[3][k] = (_Float16)v3;
            Vt[4][k] = (_Float16)v4; Vt[5][k] = (_Float16)v5;
            Vt[6][k] = (_Float16)v6; Vt[7][k] = (_Float16)v7;
            Vt[8][k] = (_Float16)1.0f;
        }
    }
    __syncthreads();

    const int e = lane & 15;
    const int g = lane >> 4;

    // Q fragments (B operand of S^T): B[kd][q], kd=(l>>4)*4+j, q=l&15.
    // Lanes >=32 cover kd 8..15 -> zero (kills garbage K products too).
    half4v qf0 = (half4v)(_Float16)0.0f;
    half4v qf1 = (half4v)(_Float16)0.0f;
    half4v qf2 = (half4v)(_Float16)0.0f;
    half4v qf3 = (half4v)(_Float16)0.0f;
    if (lane < 32) {
        const int qbase = qt * 128 + qg * 64 + e;
        qf0 = *(const half4v*)&Klds[qbase][g * 4];
        qf1 = *(const half4v*)&Klds[qbase + 16][g * 4];
        qf2 = *(const half4v*)&Klds[qbase + 32][g * 4];
        qf3 = *(const half4v*)&Klds[qbase + 48][g * 4];
    }

    const _Float16* kp = &Klds[kh * 256 + e][(g & 1) * 4]; // A: K[koff+tt*16+(l&15)][(l>>4)*4+j]
    const int ecl = (e > 8) ? 8 : e;                       // clamp: cols 9..15 unread
    const _Float16* vp = &Vt[ecl][kh * 256 + g * 4];       // B_V: V[koff+tt*16+(l>>4)*4+j][e]

    float4v acc0 = (float4v)0.0f;
    float4v acc1 = (float4v)0.0f;
    float4v acc2 = (float4v)0.0f;
    float4v acc3 = (float4v)0.0f;
    const float4v zero = (float4v)0.0f;

    // 16 key-tiles of 16; ONE kf/vf read feeds 4 q-subtiles.
#pragma unroll 4
    for (int tt = 0; tt < 16; ++tt) {
        half4v kf = *(const half4v*)(kp + tt * 128);
        half4v vf = *(const half4v*)(vp + tt * 16);

        __builtin_amdgcn_s_setprio(1);      // T5: favor this wave through MFMA+exp cluster
        float4v s0 = __builtin_amdgcn_mfma_f32_16x16x16f16(kf, qf0, zero, 0, 0, 0);
        float4v s1 = __builtin_amdgcn_mfma_f32_16x16x16f16(kf, qf1, zero, 0, 0, 0);
        float4v s2 = __builtin_amdgcn_mfma_f32_16x16x16f16(kf, qf2, zero, 0, 0, 0);
        float4v s3 = __builtin_amdgcn_mfma_f32_16x16x16f16(kf, qf3, zero, 0, 0, 0);

        float p00 = EXP2F(s0[0]), p01 = EXP2F(s0[1]), p02 = EXP2F(s0[2]), p03 = EXP2F(s0[3]);
        float p10 = EXP2F(s1[0]), p11 = EXP2F(s1[1]), p12 = EXP2F(s1[2]), p13 = EXP2F(s1[3]);
        float p20 = EXP2F(s2[0]), p21 = EXP2F(s2[1]), p22 = EXP2F(s2[2]), p23 = EXP2F(s2[3]);
        float p30 = EXP2F(s3[0]), p31 = EXP2F(s3[1]), p32 = EXP2F(s3[2]), p33 = EXP2F(s3[3]);

        half2v lo0 = __builtin_bit_cast(half2v, __builtin_amdgcn_cvt_pkrtz(p00, p01));
        half2v hi0 = __builtin_bit_cast(half2v, __builtin_amdgcn_cvt_pkrtz(p02, p03));
        half2v lo1 = __builtin_bit_cast(half2v, __builtin_amdgcn_cvt_pkrtz(p10, p11));
        half2v hi1 = __builtin_bit_cast(half2v, __builtin_amdgcn_cvt_pkrtz(p12, p13));
        half2v lo2 = __builtin_bit_cast(half2v, __builtin_amdgcn_cvt_pkrtz(p20, p21));
        half2v hi2 = __builtin_bit_cast(half2v, __builtin_amdgcn_cvt_pkrtz(p22, p23));
        half2v lo3 = __builtin_bit_cast(half2v, __builtin_amdgcn_cvt_pkrtz(p30, p31));
        half2v hi3 = __builtin_bit_cast(half2v, __builtin_amdgcn_cvt_pkrtz(p32, p33));

        half4v pa0 = __builtin_shufflevector(lo0, hi0, 0, 1, 2, 3);
        half4v pa1 = __builtin_shufflevector(lo1, hi1, 0, 1, 2, 3);
        half4v pa2 = __builtin_shufflevector(lo2, hi2, 0, 1, 2, 3);
        half4v pa3 = __builtin_shufflevector(lo3, hi3, 0, 1, 2, 3);

        acc0 = __builtin_amdgcn_mfma_f32_16x16x16f16(pa0, vf, acc0, 0, 0, 0);
        acc1 = __builtin_amdgcn_mfma_f32_16x16x16f16(pa1, vf, acc1, 0, 0, 0);
        acc2 = __builtin_amdgcn_mfma_f32_16x16x16f16(pa2, vf, acc2, 0, 0, 0);
        acc3 = __builtin_amdgcn_mfma_f32_16x16x16f16(pa3, vf, acc3, 0, 0, 0);
        __builtin_amdgcn_s_setprio(0);
    }

    // ---- kh-partial tree (unnormalized sums incl. denom col), 2 barriers ----
    if (kh >= 2) {
        scratch[kh - 2][qg][0][lane] = make_float4(acc0[0], acc0[1], acc0[2], acc0[3]);
        scratch[kh - 2][qg][1][lane] = make_float4(acc1[0], acc1[1], acc1[2], acc1[3]);
        scratch[kh - 2][qg][2][lane] = make_float4(acc2[0], acc2[1], acc2[2], acc2[3]);
        scratch[kh - 2][qg][3][lane] = make_float4(acc3[0], acc3[1], acc3[2], acc3[3]);
    }
    __syncthreads();
    if (kh < 2) {
        float4 c0 = scratch[kh][qg][0][lane];
        float4 c1 = scratch[kh][qg][1][lane];
        float4 c2 = scratch[kh][qg][2][lane];
        float4 c3 = scratch[kh][qg][3][lane];
        acc0[0] += c0.x; acc0[1] += c0.y; acc0[2] += c0.z; acc0[3] += c0.w;
        acc1[0] += c1.x; acc1[1] += c1.y; acc1[2] += c1.z; acc1[3] += c1.w;
        acc2[0] += c2.x; acc2[1] += c2.y; acc2[2] += c2.z; acc2[3] += c2.w;
        acc3[0] += c3.x; acc3[1] += c3.y; acc3[2] += c3.z; acc3[3] += c3.w;
    }
    if (kh == 1) {   // rewrite region [1] (only this wave read it)
        scratch[1][qg][0][lane] = make_float4(acc0[0], acc0[1], acc0[2], acc0[3]);
        scratch[1][qg][1][lane] = make_float4(acc1[0], acc1[1], acc1[2], acc1[3]);
        scratch[1][qg][2][lane] = make_float4(acc2[0], acc2[1], acc2[2], acc2[3]);
        scratch[1][qg][3][lane] = make_float4(acc3[0], acc3[1], acc3[2], acc3[3]);
    }
    __syncthreads();
    if (kh == 0) {
        float4 c0 = scratch[1][qg][0][lane];
        float4 c1 = scratch[1][qg][1][lane];
        float4 c2 = scratch[1][qg][2][lane];
        float4 c3 = scratch[1][qg][3][lane];
        acc0[0] += c0.x; acc0[1] += c0.y; acc0[2] += c0.z; acc0[3] += c0.w;
        acc1[0] += c1.x; acc1[1] += c1.y; acc1[2] += c1.z; acc1[3] += c1.w;
        acc2[0] += c2.x; acc2[1] += c2.y; acc2[2] += c2.z; acc2[3] += c2.w;
        acc3[0] += c3.x; acc3[1] += c3.y; acc3[2] += c3.z; acc3[3] += c3.w;

        const int src = (lane & 48) | 8;
        const size_t rb = (size_t)(b * NS + qt * 128 + qg * 64 + g * 4);
        float* opb = aout + rb * NE + h * ND + e;
#pragma unroll
        for (int qs = 0; qs < 4; ++qs) {
            float4v a = (qs == 0) ? acc0 : (qs == 1) ? acc1 : (qs == 2) ? acc2 : acc3;
            float d0 = __shfl(a[0], src, 64);
            float d1 = __shfl(a[1], src, 64);
            float d2 = __shfl(a[2], src, 64);
            float d3 = __shfl(a[3], src, 64);
            if (e < 8) {
                float* op = opb + (size_t)(qs * 16) * NE;
                op[0 * NE] = a[0] / d0;
                op[1 * NE] = a[1] / d1;
                op[2 * NE] = a[2] / d2;
                op[3 * NE] = a[3] / d3;
            }
        }
    }
}

// ---------------------------------------------------------------------------
// out = A @ W^T + b via f16 MFMA (was f32-FMA, ~128 LDS ops/thread on the
// per-CU LDS pipe ≈ 7us LDS-bound). Fragment mapping (verified in qattn):
// A_op[m][k]: m=lane&15, k=(lane>>4)*4+j;  B_op[k][n]: k=(lane>>4)*4+j,
// n=lane&15;  D[m][n]: m=(lane>>4)*4+r, n=lane&15.
// Block = 256 thr = 4 waves; block computes 16 rows x 128 cols; wave wv
// owns n-quarter [wv*32, wv*32+32) = 2 n-tiles x 8 k-chunks = 16 MFMA.
// W and A staged as f16 in LDS, row stride 140 halves (bank-spread).
// In place: block reads only the 16 rows it writes. Grid 256 blocks.
// ---------------------------------------------------------------------------
__global__ __launch_bounds__(256)
void proj_kernel(const float* __restrict__ A, const float* __restrict__ W,
                 const float* __restrict__ bias, float* __restrict__ out)
{
    __shared__ __align__(16) _Float16 Wh[NE][140];   // 35 KB: Wh[n][k]
    __shared__ __align__(16) _Float16 As[16][140];   // 4.4 KB: As[m][k]

    const int t  = threadIdx.x;
    const int r0 = blockIdx.x * 16;

    // stage A rows (f32 -> f16), vectorized float4 -> half4
    for (int i = t; i < 16 * 32; i += 256) {
        int m = i >> 5, k4 = (i & 31) * 4;
        float4 a4 = *(const float4*)&A[(size_t)(r0 + m) * NE + k4];
        half2v h01 = __builtin_bit_cast(half2v, __builtin_amdgcn_cvt_pkrtz(a4.x, a4.y));
        half2v h23 = __builtin_bit_cast(half2v, __builtin_amdgcn_cvt_pkrtz(a4.z, a4.w));
        *(half4v*)&As[m][k4] = __builtin_shufflevector(h01, h23, 0, 1, 2, 3);
    }
    // stage W (f32 -> f16)
    for (int i = t; i < NE * 32; i += 256) {
        int n = i >> 5, k4 = (i & 31) * 4;
        float4 w4 = *(const float4*)&W[(size_t)n * NE + k4];
        half2v h01 = __builtin_bit_cast(half2v, __builtin_amdgcn_cvt_pkrtz(w4.x, w4.y));
        half2v h23 = __builtin_bit_cast(half2v, __builtin_amdgcn_cvt_pkrtz(w4.z, w4.w));
        *(half4v*)&Wh[n][k4] = __builtin_shufflevector(h01, h23, 0, 1, 2, 3);
    }
    __syncthreads();

    const int lane = t & 63;
    const int wv   = t >> 6;        // n-quarter
    const int e    = lane & 15;
    const int g    = lane >> 4;

    float4v acc0 = (float4v)0.0f;
    float4v acc1 = (float4v)0.0f;

#pragma unroll
    for (int c = 0; c < 8; ++c) {
        half4v af  = *(const half4v*)&As[e][c * 16 + g * 4];
        half4v bf0 = *(const half4v*)&Wh[wv * 32 + e][c * 16 + g * 4];
        half4v bf1 = *(const half4v*)&Wh[wv * 32 + 16 + e][c * 16 + g * 4];
        acc0 = __builtin_amdgcn_mfma_f32_16x16x16f16(af, bf0, acc0, 0, 0, 0);
        acc1 = __builtin_amdgcn_mfma_f32_16x16x16f16(af, bf1, acc1, 0, 0, 0);
    }

    // D[m][n]: m = g*4 + r (row of A), n = lane&15 (col within n-tile).
    // NOTE: acc here is D^T of the usual view: A_op=A (m=e rows), B_op=W^T.
    // D[m=e? no]: with A_op rows m=lane&15 as A-row index and D rows from
    // (lane>>4)*4+r — A-row index in D is the M dim: D[g*4+r][e].
    // But A_op[m][k] had m=lane&15 = A-row -> D M-dim = A-rows: D rows g*4+r
    // correspond to A rows g*4+r; cols e = W row (output col).
    const float bv0 = bias[wv * 32 + e];
    const float bv1 = bias[wv * 32 + 16 + e];
    float* ob = out + (size_t)(r0 + g * 4) * NE + wv * 32 + e;
#pragma unroll
    for (int r = 0; r < 4; ++r) {
        ob[(size_t)r * NE]      = acc0[r] + bv0;
        ob[(size_t)r * NE + 16] = acc1[r] + bv1;
    }
}

extern "C" void kernel_launch(void* const* d_in, const int* in_sizes, int n_in,
                              void* d_out, int out_size, void* d_ws, size_t ws_size,
                              hipStream_t stream)
{
    (void)in_sizes; (void)n_in; (void)out_size; (void)d_ws; (void)ws_size;
    const float* x   = (const float*)d_in[0];
    const float* phi = (const float*)d_in[1];
    const float* W   = (const float*)d_in[2];
    const float* b   = (const float*)d_in[3];
    float* out = (float*)d_out;

    qattn_kernel<<<dim3(NB * NH * 8), dim3(512), 0, stream>>>(x, phi, out);
    proj_kernel<<<dim3(NB * NS / 16), dim3(256), 0, stream>>>(out, W, b, out);
}